// Round 3
// baseline (143.321 us; speedup 1.0000x reference)
//
#include <hip/hip_runtime.h>

typedef __attribute__((ext_vector_type(4))) float f32x4;
typedef __attribute__((ext_vector_type(8))) short bf16x8;

static __device__ __forceinline__ unsigned short f2bf(float f) {
    union { float f; unsigned int u; } v; v.f = f;
    unsigned int u = v.u;
    u += 0x7fffu + ((u >> 16) & 1u);   // round-to-nearest-even
    return (unsigned short)(u >> 16);
}

// prep: blocks 0..255 convert adj fp32->bf16 (row-major, k-contig for phase 2);
//       blocks 256..511 build Wt[n][k] = W[k][n] in bf16 (k-contig for phase 1).
__global__ void prep(const float* __restrict__ adj, const float* __restrict__ W,
                     unsigned short* __restrict__ adjb,
                     unsigned short* __restrict__ wtb) {
    int b = blockIdx.x, t = threadIdx.x;
    if (b < 256) {
        int i = b * 256 + t;
        float4 v = reinterpret_cast<const float4*>(adj)[i];
        ushort4 o;
        o.x = f2bf(v.x); o.y = f2bf(v.y); o.z = f2bf(v.z); o.w = f2bf(v.w);
        reinterpret_cast<ushort4*>(adjb)[i] = o;
    } else {
        int k = b - 256;                         // 0..255
        wtb[t * 256 + k] = f2bf(W[k * 256 + t]);
    }
}

// Fused: block = (d-slice dq of 64 cols, batch b).
// Phase 1: h_tile[d][j] = (x_b @ W[:, slice])^T  -> LDS (bf16, XOR-swizzled 16B chunks)
// Phase 2: out_b[:, slice] = adj @ h_tile        -> global fp32
// No __syncthreads inside either K-loop; one barrier between phases.
__global__ __launch_bounds__(256, 1) void fused(
    const float* __restrict__ x,
    const unsigned short* __restrict__ wtb,
    const unsigned short* __restrict__ adjb,
    float* __restrict__ out)
{
    __shared__ __align__(16) unsigned short ht[64 * 512];   // 64 KiB

    const int tid  = threadIdx.x;
    const int lane = tid & 63;
    const int wave = tid >> 6;
    const int l15  = lane & 15;
    const int quad = lane >> 4;
    const int dq   = blockIdx.x;     // 0..3  (64-col slice of d_out)
    const int b    = blockIdx.y;     // 0..63 (graph)
    const int mW   = wave * 128;     // this wave's 128-row range (both phases)

    f32x4 acc[8][4];
#pragma unroll
    for (int mi = 0; mi < 8; mi++)
#pragma unroll
        for (int ni = 0; ni < 4; ni++) acc[mi][ni] = (f32x4){0.f, 0.f, 0.f, 0.f};

    // ---------------- Phase 1: h_slice = x_b @ W[:, dq*64 .. +64) ----------------
    const float* xb = x + (size_t)b * 512 * 256;

#pragma unroll 2
    for (int k0 = 0; k0 < 256; k0 += 32) {
        bf16x8 bfrag[4];
#pragma unroll
        for (int ni = 0; ni < 4; ni++) {
            int n = dq * 64 + ni * 16 + l15;
            bfrag[ni] = *reinterpret_cast<const bf16x8*>(wtb + n * 256 + k0 + quad * 8);
        }
#pragma unroll
        for (int mi = 0; mi < 8; mi++) {
            int row = mW + mi * 16 + l15;     // node j within batch
            const float4* px = reinterpret_cast<const float4*>(
                xb + (size_t)row * 256 + k0 + quad * 8);
            float4 v0 = px[0], v1 = px[1];
            union { bf16x8 v; unsigned short u[8]; } a;
            a.u[0] = f2bf(v0.x); a.u[1] = f2bf(v0.y);
            a.u[2] = f2bf(v0.z); a.u[3] = f2bf(v0.w);
            a.u[4] = f2bf(v1.x); a.u[5] = f2bf(v1.y);
            a.u[6] = f2bf(v1.z); a.u[7] = f2bf(v1.w);
#pragma unroll
            for (int ni = 0; ni < 4; ni++)
                acc[mi][ni] = __builtin_amdgcn_mfma_f32_16x16x32_bf16(
                    a.v, bfrag[ni], acc[mi][ni], 0, 0, 0);
        }
    }

    // Write h_tile[d_local][node] bf16, XOR-swizzled at 16B-chunk granularity:
    // physical chunk = (node/8) ^ (d_local & 7).
#pragma unroll
    for (int mi = 0; mi < 8; mi++) {
        int m = mW + mi * 16 + quad * 4;      // node index (4 consecutive via regs)
#pragma unroll
        for (int ni = 0; ni < 4; ni++) {
            int n = ni * 16 + l15;            // d_local
            int chunk = (m >> 3) ^ (n & 7);
            ushort4 p;
            p.x = f2bf(acc[mi][ni][0]); p.y = f2bf(acc[mi][ni][1]);
            p.z = f2bf(acc[mi][ni][2]); p.w = f2bf(acc[mi][ni][3]);
            *reinterpret_cast<ushort4*>(ht + n * 512 + chunk * 8 + (m & 7)) = p;
        }
    }
    __syncthreads();

    // ---------------- Phase 2: out_b[:, slice] = adj @ h_slice ----------------
#pragma unroll
    for (int mi = 0; mi < 8; mi++)
#pragma unroll
        for (int ni = 0; ni < 4; ni++) acc[mi][ni] = (f32x4){0.f, 0.f, 0.f, 0.f};

#pragma unroll 2
    for (int k0 = 0; k0 < 512; k0 += 32) {
        bf16x8 bfrag[4];
#pragma unroll
        for (int ni = 0; ni < 4; ni++) {
            int n = ni * 16 + l15;            // d_local
            int chunk = ((k0 >> 3) + quad) ^ (n & 7);
            bfrag[ni] = *reinterpret_cast<const bf16x8*>(ht + n * 512 + chunk * 8);
        }
#pragma unroll
        for (int mi = 0; mi < 8; mi++) {
            int row = mW + mi * 16 + l15;     // out node row i
            bf16x8 a = *reinterpret_cast<const bf16x8*>(
                adjb + (size_t)row * 512 + k0 + quad * 8);
#pragma unroll
            for (int ni = 0; ni < 4; ni++)
                acc[mi][ni] = __builtin_amdgcn_mfma_f32_16x16x32_bf16(
                    a, bfrag[ni], acc[mi][ni], 0, 0, 0);
        }
    }

    // Epilogue: out[(b*512 + i) * 256 + dq*64 + d_local], fp32.
    float* ob = out + ((size_t)b * 512) * 256 + dq * 64;
#pragma unroll
    for (int mi = 0; mi < 8; mi++) {
        int i0 = mW + mi * 16 + quad * 4;
#pragma unroll
        for (int ni = 0; ni < 4; ni++) {
            int d = ni * 16 + l15;
#pragma unroll
            for (int r = 0; r < 4; r++)
                ob[(size_t)(i0 + r) * 256 + d] = acc[mi][ni][r];
        }
    }
}

extern "C" void kernel_launch(void* const* d_in, const int* in_sizes, int n_in,
                              void* d_out, int out_size, void* d_ws, size_t ws_size,
                              hipStream_t stream) {
    const float* x   = (const float*)d_in[0];
    // d_in[1] = batch ids (unused; block-contiguous layout by construction)
    const float* W   = (const float*)d_in[2];
    const float* Adj = (const float*)d_in[3];
    float* out = (float*)d_out;

    unsigned short* adjb = (unsigned short*)d_ws;   // 262144 elems (512 KB)
    unsigned short* wtb  = adjb + 262144;           // 65536 elems  (128 KB)

    prep<<<512, 256, 0, stream>>>(Adj, W, adjb, wtb);
    fused<<<dim3(4, 64), 256, 0, stream>>>(x, wtb, adjb, out);
}

// Round 4
// 110.427 us; speedup vs baseline: 1.2979x; 1.2979x over previous
//
#include <hip/hip_runtime.h>

typedef __attribute__((ext_vector_type(4))) float f32x4;
typedef __attribute__((ext_vector_type(8))) short bf16x8;

static __device__ __forceinline__ unsigned short f2bf(float f) {
    union { float f; unsigned int u; } v; v.f = f;
    unsigned int u = v.u;
    u += 0x7fffu + ((u >> 16) & 1u);   // round-to-nearest-even
    return (unsigned short)(u >> 16);
}

// prep: permute inputs into MFMA fragment-order bf16 buffers.
// Fragment chunk = 16 (m|n) x 32 (k) tile stored as [lane][8] bf16 (1 KB),
// lane = ((k&31)>>3)*16 + (m&15), elem jj = k&7.
//   xfrag  chunk c  = (b*8 + k0g)*32 + m0          (16384 chunks)
//   adjfrag chunk c2 = k0g*32 + m0                 (512 chunks)
//   wtfrag chunk c3 = k0g*16 + n0   (Wt[n][k]=W[k][n], 128 chunks)
__global__ __launch_bounds__(256) void prep(
    const float* __restrict__ x, const float* __restrict__ adj,
    const float* __restrict__ W,
    unsigned short* __restrict__ xf, unsigned short* __restrict__ af,
    unsigned short* __restrict__ wf)
{
    const int wave = threadIdx.x >> 6, lane = threadIdx.x & 63;
    const int l15 = lane & 15, quad = lane >> 4;
    const int c = blockIdx.x * 4 + wave;     // 0..17023, wave-uniform

    float t[8];
    unsigned short* dst;
    if (c < 16384) {
        int b = c >> 8, k0g = (c >> 5) & 7, m0 = c & 31;
        const float* src = x + ((size_t)(b * 512 + m0 * 16 + l15)) * 256 + k0g * 32 + quad * 8;
        float4 f0 = *reinterpret_cast<const float4*>(src);
        float4 f1 = *reinterpret_cast<const float4*>(src + 4);
        t[0]=f0.x; t[1]=f0.y; t[2]=f0.z; t[3]=f0.w;
        t[4]=f1.x; t[5]=f1.y; t[6]=f1.z; t[7]=f1.w;
        dst = xf + (size_t)c * 512 + lane * 8;
    } else if (c < 16896) {
        int c2 = c - 16384, k0g = c2 >> 5, m0 = c2 & 31;
        const float* src = adj + ((size_t)(m0 * 16 + l15)) * 512 + k0g * 32 + quad * 8;
        float4 f0 = *reinterpret_cast<const float4*>(src);
        float4 f1 = *reinterpret_cast<const float4*>(src + 4);
        t[0]=f0.x; t[1]=f0.y; t[2]=f0.z; t[3]=f0.w;
        t[4]=f1.x; t[5]=f1.y; t[6]=f1.z; t[7]=f1.w;
        dst = af + (size_t)c2 * 512 + lane * 8;
    } else {
        int c3 = c - 16896, k0g = c3 >> 4, n0 = c3 & 15;
        int k = k0g * 32 + quad * 8, n = n0 * 16 + l15;
#pragma unroll
        for (int jj = 0; jj < 8; jj++) t[jj] = W[(size_t)(k + jj) * 256 + n];
        dst = wf + (size_t)c3 * 512 + lane * 8;
    }
    union { unsigned short u[8]; uint4 q; } o;
#pragma unroll
    for (int jj = 0; jj < 8; jj++) o.u[jj] = f2bf(t[jj]);
    *reinterpret_cast<uint4*>(dst) = o.q;
}

// Fused: block = (batch-pair bp, 32-col d-slice dq). 512 threads (8 waves).
// Phase 1: h[bb][512 j][32 d] = x_b @ W[:,slice] -> LDS in phase-2 B-frag order.
// Phase 2: out_b[:, slice] = adj @ h.  No barriers inside K-loops.
__global__ __launch_bounds__(512, 2) void fused(
    const unsigned short* __restrict__ xf,
    const unsigned short* __restrict__ wf,
    const unsigned short* __restrict__ af,
    float* __restrict__ out)
{
    // ht[bb][k0g][ni][lane][8] : 2*16*2*64*8 bf16 = 64 KiB
    __shared__ __align__(16) unsigned short ht[32768];

    const int tid  = threadIdx.x;
    const int lane = tid & 63, wave = tid >> 6;
    const int l15  = lane & 15, quad = lane >> 4;
    const int bp   = blockIdx.x;   // 0..31 (fast dim -> 8 dq-blocks of a bp share an XCD)
    const int dq   = blockIdx.y;   // 0..7
    const int b0   = bp * 2;

    f32x4 acc[2][4][2];
#pragma unroll
    for (int bb = 0; bb < 2; bb++)
#pragma unroll
        for (int mi = 0; mi < 4; mi++)
#pragma unroll
            for (int ni = 0; ni < 2; ni++) acc[bb][mi][ni] = (f32x4){0.f,0.f,0.f,0.f};

    // ---------------- Phase 1: K=256, 8 k-steps ----------------
#pragma unroll 2
    for (int k0g = 0; k0g < 8; k0g++) {
        bf16x8 bw[2];
#pragma unroll
        for (int ni = 0; ni < 2; ni++)
            bw[ni] = *reinterpret_cast<const bf16x8*>(
                wf + ((size_t)((k0g * 16 + dq * 2 + ni) * 64) + lane) * 8);
        bf16x8 a[2][4];
#pragma unroll
        for (int bb = 0; bb < 2; bb++)
#pragma unroll
            for (int mi = 0; mi < 4; mi++)
                a[bb][mi] = *reinterpret_cast<const bf16x8*>(
                    xf + ((size_t)((((b0 + bb) * 8 + k0g) * 32 + wave * 4 + mi) * 64) + lane) * 8);
#pragma unroll
        for (int bb = 0; bb < 2; bb++)
#pragma unroll
            for (int mi = 0; mi < 4; mi++)
#pragma unroll
                for (int ni = 0; ni < 2; ni++)
                    acc[bb][mi][ni] = __builtin_amdgcn_mfma_f32_16x16x32_bf16(
                        a[bb][mi], bw[ni], acc[bb][mi][ni], 0, 0, 0);
    }

    // Epilogue: write h into phase-2 B-fragment order.
    // value (j, d): j = wave*64 + mi*16 + quad*4 + r, d = dq*32 + ni*16 + l15
#pragma unroll
    for (int bb = 0; bb < 2; bb++)
#pragma unroll
        for (int mi = 0; mi < 4; mi++) {
            int k0g2  = wave * 2 + (mi >> 1);
            int quadp = (mi & 1) * 2 + (quad >> 1);
#pragma unroll
            for (int ni = 0; ni < 2; ni++) {
                ushort4 p;
                p.x = f2bf(acc[bb][mi][ni][0]); p.y = f2bf(acc[bb][mi][ni][1]);
                p.z = f2bf(acc[bb][mi][ni][2]); p.w = f2bf(acc[bb][mi][ni][3]);
                *reinterpret_cast<ushort4*>(
                    ht + ((bb * 32 + k0g2 * 2 + ni) * 64 + quadp * 16 + l15) * 8
                       + (quad & 1) * 4) = p;
            }
        }
    __syncthreads();

    // ---------------- Phase 2: K=512, 16 k-steps ----------------
    f32x4 o[2][4][2];
#pragma unroll
    for (int bb = 0; bb < 2; bb++)
#pragma unroll
        for (int mi = 0; mi < 4; mi++)
#pragma unroll
            for (int ni = 0; ni < 2; ni++) o[bb][mi][ni] = (f32x4){0.f,0.f,0.f,0.f};

#pragma unroll 2
    for (int k0g = 0; k0g < 16; k0g++) {
        bf16x8 a[4];
#pragma unroll
        for (int mi = 0; mi < 4; mi++)
            a[mi] = *reinterpret_cast<const bf16x8*>(
                af + ((size_t)((k0g * 32 + wave * 4 + mi) * 64) + lane) * 8);
        bf16x8 hb[2][2];
#pragma unroll
        for (int bb = 0; bb < 2; bb++)
#pragma unroll
            for (int ni = 0; ni < 2; ni++)
                hb[bb][ni] = *reinterpret_cast<const bf16x8*>(
                    ht + ((bb * 32 + k0g * 2 + ni) * 64 + lane) * 8);
#pragma unroll
        for (int bb = 0; bb < 2; bb++)
#pragma unroll
            for (int mi = 0; mi < 4; mi++)
#pragma unroll
                for (int ni = 0; ni < 2; ni++)
                    o[bb][mi][ni] = __builtin_amdgcn_mfma_f32_16x16x32_bf16(
                        a[mi], hb[bb][ni], o[bb][mi][ni], 0, 0, 0);
    }

    // Store out fp32: row i = wave*64 + mi*16 + quad*4 + r, col dq*32 + ni*16 + l15
#pragma unroll
    for (int bb = 0; bb < 2; bb++) {
        float* ob = out + ((size_t)(b0 + bb) * 512) * 256 + dq * 32;
#pragma unroll
        for (int mi = 0; mi < 4; mi++) {
            int i0 = wave * 64 + mi * 16 + quad * 4;
#pragma unroll
            for (int ni = 0; ni < 2; ni++) {
                int d = ni * 16 + l15;
#pragma unroll
                for (int r = 0; r < 4; r++)
                    ob[(size_t)(i0 + r) * 256 + d] = o[bb][mi][ni][r];
            }
        }
    }
}

extern "C" void kernel_launch(void* const* d_in, const int* in_sizes, int n_in,
                              void* d_out, int out_size, void* d_ws, size_t ws_size,
                              hipStream_t stream) {
    const float* x   = (const float*)d_in[0];
    // d_in[1] = batch ids (unused; block-contiguous layout by construction)
    const float* W   = (const float*)d_in[2];
    const float* Adj = (const float*)d_in[3];
    float* out = (float*)d_out;

    unsigned short* xfrag = (unsigned short*)d_ws;    // 8388608 elems (16 MB)
    unsigned short* afrag = xfrag + 8388608;          // 262144 elems (512 KB)
    unsigned short* wfrag = afrag + 262144;           // 65536 elems (128 KB)

    prep<<<4256, 256, 0, stream>>>(x, Adj, W, xfrag, afrag, wfrag);
    fused<<<dim3(32, 8), 512, 0, stream>>>(xfrag, wfrag, afrag, out);
}